// Round 7
// baseline (255.646 us; speedup 1.0000x reference)
//
#include <hip/hip_runtime.h>

#define TPB 512

typedef _Float16 hf2 __attribute__((ext_vector_type(2)));

__device__ __forceinline__ hf2 as_h2(unsigned u) { return __builtin_bit_cast(hf2, u); }
__device__ __forceinline__ unsigned pk2h(float a, float b) {
    unsigned la = (unsigned)__builtin_bit_cast(unsigned short, (_Float16)a);
    unsigned hb = (unsigned)__builtin_bit_cast(unsigned short, (_Float16)b);
    return la | (hb << 16);
}
__device__ __forceinline__ unsigned short h16(float a) {
    return __builtin_bit_cast(unsigned short, (_Float16)a);
}
#define FDOT2(w, x, acc) __builtin_amdgcn_fdot2(as_h2(w), as_h2(x), (acc), false)

// wave-uniform broadcast: pull packed f16 pair from lane `l` of `v` into an SGPR
__device__ __forceinline__ unsigned rdl(unsigned v, int l) {
    return (unsigned)__builtin_amdgcn_readlane((int)v, l);
}

#define G16(M) M(0) M(1) M(2) M(3) M(4) M(5) M(6) M(7) M(8) M(9) M(10) M(11) \
  M(12) M(13) M(14) M(15)

#define RED64(v) { v += __shfl_xor(v,32,64); v += __shfl_xor(v,16,64); \
  v += __shfl_xor(v,8,64); v += __shfl_xor(v,4,64); v += __shfl_xor(v,2,64); \
  v += __shfl_xor(v,1,64); }

// One block per sample (128 blocks). Round-5 was LDS-issue-bound: 48 ds_reads
// /thread/eval, 32 of them 16B-useful broadcasts. This version: operand
// vectors (x, a-slice) are loaded ONCE per wave as one packed u32/lane
// (ds_read_b32), then distributed via v_readlane -> SGPR src of v_dot2_f32_f16
// (VALU/SALU path, DS pipe untouched). 18 ds_reads/thread/eval remain
// (16 W1L b128 + 2 b32).
//   - W2 col j f16-packed in 64 named scalar u32 regs (persistent)
//   - W1 f16 in LDS, W1L[c][t] = rows 8c..8c+7 of col t (16B, conflict-free)
__global__ __launch_bounds__(TPB, 1) void vi_node_kernel(
    const float* __restrict__ x0, const float* __restrict__ W1,
    const float* __restrict__ b1, const float* __restrict__ u1,
    const float* __restrict__ W2, const float* __restrict__ b2,
    const int* __restrict__ nsp, float* __restrict__ out, int nB)
{
    const int s    = blockIdx.x;
    const int t    = threadIdx.x;
    const int j    = t & 127;
    const int q    = t >> 7;
    const int kb   = q << 7;
    const int lane = t & 63;
    const int wid  = t >> 6;

    __shared__ uint4 W1L[16 * 512];                 // 128 KB, f16 W1 columns
    __shared__ __align__(16) float    xs32[128];    // stage input, fp32
    __shared__ __align__(8)  unsigned xsPK[64];     // stage input, f16 pairs
    __shared__ __align__(16) float    ys[128];      // base state y_n
    __shared__ __align__(8)  unsigned aPK[256];     // tanh acts, f16 pairs
    __shared__ __align__(16) float    part[4][128]; // dxdt partials
    __shared__ __align__(16) float    kx[6][128];   // RK stage slopes
    __shared__ float wredT[2][6][8];                // trace partials [par][stage][wave]
    __shared__ float wredX[2][6][2];                // x.dx partials  [par][stage][wave0/1]
    __shared__ float sqred[2];

    // ---- build W1L (global reads coalesced across t for each row) ----
#pragma unroll
    for (int c = 0; c < 16; ++c) {
        const float* gp = W1 + (8 * c) * 512 + t;
        uint4 wv;
        wv.x = pk2h(gp[0],        gp[512]);
        wv.y = pk2h(gp[2 * 512],  gp[3 * 512]);
        wv.z = pk2h(gp[4 * 512],  gp[5 * 512]);
        wv.w = pk2h(gp[6 * 512],  gp[7 * 512]);
        W1L[c * 512 + t] = wv;
    }

    // ---- W2 column j, rows kb..kb+127, f16 pairs in named scalar regs ----
#define DECLZ(g) unsigned z_##g##_0, z_##g##_1, z_##g##_2, z_##g##_3;
    G16(DECLZ)
#define PKW2(r) pk2h(W2[(r) * 128 + j], W2[((r) + 1) * 128 + j])
#define LOADZ(g) { const int r_ = kb + 8 * (g); \
    z_##g##_0 = PKW2(r_);     z_##g##_1 = PKW2(r_ + 2); \
    z_##g##_2 = PKW2(r_ + 4); z_##g##_3 = PKW2(r_ + 6); }
    G16(LOADZ)

    const float b1k = b1[t];
    const float u1k = u1[t];
    const float b2j = b2[j];

    const int ns = nsp[0];
    const float dt = 1.f / (float)ns;

    // ---- x0 init + log_px0 sum of squares ----
    if (t < 128) {
        float xv0 = x0[s * 128 + t];
        ys[t] = xv0;
        xs32[t] = xv0;
        ((unsigned short*)xsPK)[t] = h16(xv0);
        float sq = xv0 * xv0;
        RED64(sq)
        if (lane == 0) sqred[wid] = sq;
    }
    __syncthreads();   // W1L + xsPK + sqred ready

    // ---- wdiag_t = sum_i W1[i,t]*W2[t,i] via f16 dot2 (one-time) ----
    float wd = 0.f;
    {
        const float4* w2r4 = (const float4*)(W2 + t * 128);
#pragma unroll
        for (int c = 0; c < 16; ++c) {
            uint4 wv = W1L[c * 512 + t];
            float4 a4 = w2r4[2 * c], b4 = w2r4[2 * c + 1];
            wd = FDOT2(wv.x, pk2h(a4.x, a4.y), wd);
            wd = FDOT2(wv.y, pk2h(a4.z, a4.w), wd);
            wd = FDOT2(wv.z, pk2h(b4.x, b4.y), wd);
            wd = FDOT2(wv.w, pk2h(b4.z, b4.w), wd);
        }
    }
    const float sumsq = sqred[0] + sqred[1];
    float ld_acc = 0.f, kl_acc = 0.f;   // thread-0 accumulators

    // ---- per-eval compute groups (x/a pairs come via readlane -> SGPR) ----
#define H4(c) { uint4 w_ = W1L[(c) * 512 + t]; \
    m0 = FDOT2(w_.x, rdl(xv, 4*(c)+0), m0); \
    m1 = FDOT2(w_.y, rdl(xv, 4*(c)+1), m1); \
    m2 = FDOT2(w_.z, rdl(xv, 4*(c)+2), m2); \
    m3 = FDOT2(w_.w, rdl(xv, 4*(c)+3), m3); }

#define P4(g) { \
    p0 = FDOT2(z_##g##_0, rdl(av, 4*(g)+0), p0); \
    p1 = FDOT2(z_##g##_1, rdl(av, 4*(g)+1), p1); \
    p2 = FDOT2(z_##g##_2, rdl(av, 4*(g)+2), p2); \
    p3 = FDOT2(z_##g##_3, rdl(av, 4*(g)+3), p3); }

#define K(sidx) kx[sidx][t]

// One RHS eval + in-place state advance. 3 barriers.
#define EVAL(STAGE, TVAL, XNEW, EXTRA)                                         \
    {                                                                          \
        const unsigned xv = xsPK[lane];            /* whole x in one wave-reg */\
        float m0 = 0.f, m1 = 0.f, m2 = 0.f, m3 = 0.f;                          \
        H4(0) H4(1) H4(2) H4(3) H4(4) H4(5) H4(6) H4(7)                        \
        H4(8) H4(9) H4(10) H4(11) H4(12) H4(13) H4(14) H4(15)                  \
        float hh = fmaf((TVAL), u1k, b1k) + ((m0 + m1) + (m2 + m3));           \
        float ee = __expf(2.f * hh);                                           \
        float aa = 1.f - 2.f / (ee + 1.f);       /* tanh */                    \
        ((unsigned short*)aPK)[t] = h16(aa);                                   \
        float trp = (1.f - aa * aa) * wd;                                      \
        RED64(trp)                                                             \
        if (lane == 0) wredT[par][STAGE][wid] = trp;                           \
        __syncthreads();                          /* B1: aPK + trace ready */  \
        const unsigned av = aPK[(q << 6) + lane]; /* wave slice in one reg */  \
        float p0 = 0.f, p1 = 0.f, p2 = 0.f, p3 = 0.f;                          \
        P4(0) P4(1) P4(2) P4(3) P4(4) P4(5) P4(6) P4(7)                        \
        P4(8) P4(9) P4(10) P4(11) P4(12) P4(13) P4(14) P4(15)                  \
        part[q][j] = (p0 + p1) + (p2 + p3);                                    \
        __syncthreads();                          /* B2: partials ready */     \
        if (t < 128) {                                                         \
            float dx = ((part[0][t] + part[1][t]) + (part[2][t] + part[3][t])) \
                       + b2j;                                                  \
            kx[STAGE][t] = dx;                                                 \
            float xd = xs32[t] * dx;                                           \
            RED64(xd)                                                          \
            if (lane == 0) wredX[par][STAGE][wid] = xd;                        \
            float xnew = (XNEW);                                               \
            xs32[t] = xnew;                                                    \
            ((unsigned short*)xsPK)[t] = h16(xnew);                            \
            EXTRA                                                              \
        }                                                                      \
        __syncthreads();                          /* B3: state advanced */     \
    }

    for (int n = 0; n < ns; ++n) {
        const float tn = (float)n;
        const int par = n & 1;

        EVAL(0, dt * tn,
             fmaf(dt, 0.2f * dx, ys[t]), ;)

        EVAL(1, dt * (tn + 0.2f),
             ys[t] + dt * (0.075f * K(0) + 0.225f * dx), ;)

        EVAL(2, dt * (tn + 0.3f),
             ys[t] + dt * ((float)(44.0/45.0)  * K(0) + (float)(-56.0/15.0) * K(1)
                         + (float)(32.0/9.0)   * dx), ;)

        EVAL(3, dt * (tn + 0.8f),
             ys[t] + dt * ((float)(19372.0/6561.0) * K(0) + (float)(-25360.0/2187.0) * K(1)
                         + (float)(64448.0/6561.0) * K(2) + (float)(-212.0/729.0)    * dx), ;)

        EVAL(4, dt * (tn + (float)(8.0/9.0)),
             ys[t] + dt * ((float)(9017.0/3168.0)  * K(0) + (float)(-355.0/33.0)     * K(1)
                         + (float)(46732.0/5247.0) * K(2) + (float)(49.0/176.0)      * K(3)
                         + (float)(-5103.0/18656.0)* dx), ;)

        EVAL(5, dt * (tn + 1.0f),
             ys[t] + dt * ((float)(35.0/384.0)     * K(0) + (float)(500.0/1113.0)   * K(2)
                         + (float)(125.0/192.0)    * K(3) + (float)(-2187.0/6784.0) * K(4)
                         + (float)(11.0/84.0)      * dx),
             ys[t] = xnew;)

        // serial tail once per STEP: weighted log-det / KL accumulation.
        // wredT/wredX[par] slots stable: next same-parity write is 2 steps away.
        if (t == 0) {
#define TAILS(sidx, bw) { \
            float tr_ = ((wredT[par][sidx][0] + wredT[par][sidx][1])  \
                       + (wredT[par][sidx][2] + wredT[par][sidx][3])) \
                      + ((wredT[par][sidx][4] + wredT[par][sidx][5])  \
                       + (wredT[par][sidx][6] + wredT[par][sidx][7])); \
            float dv_ = wredX[par][sidx][0] + wredX[par][sidx][1]; \
            ld_acc += dt * (bw) * (-tr_); \
            kl_acc += dt * (bw) * (dv_ - tr_); }
            TAILS(0, (float)(35.0/384.0))
            TAILS(2, (float)(500.0/1113.0))
            TAILS(3, (float)(125.0/192.0))
            TAILS(4, (float)(-2187.0/6784.0))
            TAILS(5, (float)(11.0/84.0))
        }
    }

    // ---- outputs: z (B,D) | log_px (B) | kl (B) ----
    if (t < 128) out[s * 128 + t] = ys[t];
    if (t == 0) {
        const float LOG2PI = 1.8378770664093454f;
        float lpx0 = -0.5f * sumsq - 0.5f * 128.f * LOG2PI;
        out[nB * 128 + s]      = lpx0 + ld_acc;
        out[nB * 128 + nB + s] = kl_acc;
    }
}

extern "C" void kernel_launch(void* const* d_in, const int* in_sizes, int n_in,
                              void* d_out, int out_size, void* d_ws, size_t ws_size,
                              hipStream_t stream) {
    const float* x0 = (const float*)d_in[0];
    const float* W1 = (const float*)d_in[1];
    const float* b1 = (const float*)d_in[2];
    const float* u1 = (const float*)d_in[3];
    const float* W2 = (const float*)d_in[4];
    const float* b2 = (const float*)d_in[5];
    const int*  nsp = (const int*)d_in[6];
    float* out = (float*)d_out;
    const int nB = in_sizes[0] / 128;   // 128 samples

    hipLaunchKernelGGL(vi_node_kernel, dim3(nB), dim3(TPB), 0, stream,
                       x0, W1, b1, u1, W2, b2, nsp, out, nB);
}

// Round 8
// 237.947 us; speedup vs baseline: 1.0744x; 1.0744x over previous
//
#include <hip/hip_runtime.h>

#define TPB 1024

typedef _Float16 hf2 __attribute__((ext_vector_type(2)));

__device__ __forceinline__ hf2 as_h2(unsigned u) { return __builtin_bit_cast(hf2, u); }
__device__ __forceinline__ unsigned pk2h(float a, float b) {
    unsigned la = (unsigned)__builtin_bit_cast(unsigned short, (_Float16)a);
    unsigned hb = (unsigned)__builtin_bit_cast(unsigned short, (_Float16)b);
    return la | (hb << 16);
}
__device__ __forceinline__ unsigned short h16(float a) {
    return __builtin_bit_cast(unsigned short, (_Float16)a);
}
#define FDOT2(w, x, acc) __builtin_amdgcn_fdot2(as_h2(w), as_h2(x), (acc), false)

#define G8(M) M(0) M(1) M(2) M(3) M(4) M(5) M(6) M(7)

#define RED64(v) { v += __shfl_xor(v,32,64); v += __shfl_xor(v,16,64); \
  v += __shfl_xor(v,8,64); v += __shfl_xor(v,4,64); v += __shfl_xor(v,2,64); \
  v += __shfl_xor(v,1,64); }

// One block per sample, 1024 threads (16 waves, 4/SIMD for latency hiding;
// round-5's 2 waves/SIMD couldn't hide DS+chain latency, round-7 showed
// readlane distribution is WORSE than LDS broadcast).
//   H-phase: 2 threads per hidden unit h=32w+(l&31); halves (l vs l+32)
//            combined by one shfl_xor(32). W1 f16 in LDS (conflict-free
//            pattern identical to round 5's measured-zero-conflict layout).
//   P-phase: 8 groups x 128 outputs; W2 slice in 32 persistent VGPRs
//            (half of round 5/7 -> total ~80 VGPR, under the 128 wall,
//            so the residual 7 MB spill should disappear).
//   Operands (x, a) distributed via b128 LDS broadcast (r5 style).
__global__ __launch_bounds__(TPB, 1) void vi_node_kernel(
    const float* __restrict__ x0, const float* __restrict__ W1,
    const float* __restrict__ b1, const float* __restrict__ u1,
    const float* __restrict__ W2, const float* __restrict__ b2,
    const int* __restrict__ nsp, float* __restrict__ out, int nB)
{
    const int s    = blockIdx.x;
    const int t    = threadIdx.x;
    const int l    = t & 63;
    const int w    = t >> 6;          // wave 0..15
    const int h    = 32 * w + (t & 31); // hidden unit 0..511 (2 threads each)
    const int half = (t >> 5) & 1;    // which 64-row half of the H dot
    const int hb   = half * 32;       // xsPK u32 base for this half
    const int j    = t & 127;         // P output column
    const int q    = t >> 7;          // P row-block 0..7 (rows 64q..64q+63)

    __shared__ uint4 W1L[16 * 512];                 // 128 KB f16 W1, [chunk][col]
    __shared__ __align__(16) float    xs32[128];    // stage input fp32
    __shared__ __align__(16) unsigned xsPK[64];     // stage input f16 pairs
    __shared__ __align__(16) float    ys[128];      // base state
    __shared__ __align__(16) unsigned aPK[256];     // tanh acts f16 pairs
    __shared__ __align__(16) float    part[8][128]; // dxdt partials
    __shared__ __align__(16) float    kx[6][128];   // RK stage slopes
    __shared__ float wredT[2][6][16];               // trace partials [par][stage][wave]
    __shared__ float wredX[2][6][2];                // x.dx partials
    __shared__ float sqred[2];

    // ---- build W1L: thread covers col=t&511, chunks 8*(t>>9)+cc ----
    {
        const int col = t & 511;
        const int c0  = t >> 9;
#pragma unroll
        for (int cc = 0; cc < 8; ++cc) {
            const int c = 8 * c0 + cc;
            const float* gp = W1 + (8 * c) * 512 + col;   // coalesced over col
            uint4 wv;
            wv.x = pk2h(gp[0],        gp[512]);
            wv.y = pk2h(gp[2 * 512],  gp[3 * 512]);
            wv.z = pk2h(gp[4 * 512],  gp[5 * 512]);
            wv.w = pk2h(gp[6 * 512],  gp[7 * 512]);
            W1L[c * 512 + col] = wv;
        }
    }

    // ---- W2 slice: col j, rows 64q..64q+63 as f16 pairs in 32 regs ----
#define DECLZ(cc) unsigned zc_##cc##_0, zc_##cc##_1, zc_##cc##_2, zc_##cc##_3;
    G8(DECLZ)
#define PKW2(r) pk2h(W2[(r) * 128 + j], W2[((r) + 1) * 128 + j])
#define LOADZ(cc) { const int r_ = 64 * q + 8 * (cc); \
    zc_##cc##_0 = PKW2(r_);     zc_##cc##_1 = PKW2(r_ + 2); \
    zc_##cc##_2 = PKW2(r_ + 4); zc_##cc##_3 = PKW2(r_ + 6); }
    G8(LOADZ)

    const float b1k = b1[h];
    const float u1k = u1[h];
    const float b2j = b2[j];

    const int ns = nsp[0];
    const float dt = 1.f / (float)ns;

    // ---- x0 init + log_px0 sum of squares ----
    if (t < 128) {
        float xv0 = x0[s * 128 + t];
        ys[t] = xv0;
        xs32[t] = xv0;
        ((unsigned short*)xsPK)[t] = h16(xv0);
        float sq = xv0 * xv0;
        RED64(sq)
        if (l == 0) sqred[w] = sq;
    }
    __syncthreads();   // W1L + xsPK + sqred ready

    // ---- wd_h = sum_i W1[i,h]*W2[h,i]: each half-thread does its 64, shfl-combine ----
    float wd;
    {
        float wp = 0.f;
        const float4* w2r4 = (const float4*)(W2 + h * 128);
#pragma unroll
        for (int cc = 0; cc < 8; ++cc) {
            uint4 wv = W1L[(8 * half + cc) * 512 + h];
            float4 a4 = w2r4[16 * half + 2 * cc];
            float4 b4 = w2r4[16 * half + 2 * cc + 1];
            wp = FDOT2(wv.x, pk2h(a4.x, a4.y), wp);
            wp = FDOT2(wv.y, pk2h(a4.z, a4.w), wp);
            wp = FDOT2(wv.z, pk2h(b4.x, b4.y), wp);
            wp = FDOT2(wv.w, pk2h(b4.z, b4.w), wp);
        }
        wd = wp + __shfl_xor(wp, 32, 64);
    }
    const float sumsq = sqred[0] + sqred[1];
    float ld_acc = 0.f, kl_acc = 0.f;   // thread-0 accumulators

    // ---- per-eval compute groups ----
#define H4(cc) { uint4 w_ = W1L[(8 * half + (cc)) * 512 + h]; \
    const uint4 xu_ = *(const uint4*)&xsPK[hb + 4 * (cc)]; /* broadcast */ \
    m0 = FDOT2(w_.x, xu_.x, m0); m1 = FDOT2(w_.y, xu_.y, m1); \
    m2 = FDOT2(w_.z, xu_.z, m2); m3 = FDOT2(w_.w, xu_.w, m3); }

#define P4(cc) { const uint4 av_ = *(const uint4*)&aPK[32 * q + 4 * (cc)]; /* broadcast */ \
    p0 = FDOT2(zc_##cc##_0, av_.x, p0); p1 = FDOT2(zc_##cc##_1, av_.y, p1); \
    p2 = FDOT2(zc_##cc##_2, av_.z, p2); p3 = FDOT2(zc_##cc##_3, av_.w, p3); }

#define K(sidx) kx[sidx][t]

// One RHS eval + in-place state advance. 3 barriers.
#define EVAL(STAGE, TVAL, XNEW, EXTRA)                                         \
    {                                                                          \
        float m0 = 0.f, m1 = 0.f, m2 = 0.f, m3 = 0.f;                          \
        G8(H4)                                                                 \
        float mm = (m0 + m1) + (m2 + m3);                                      \
        mm += __shfl_xor(mm, 32, 64);             /* combine the two halves */ \
        if ((t & 32) == 0) {                      /* lower half owns unit h */ \
            float hh = fmaf((TVAL), u1k, b1k) + mm;                            \
            float ee = __expf(2.f * hh);                                       \
            float aa = 1.f - 2.f / (ee + 1.f);    /* tanh */                   \
            ((unsigned short*)aPK)[h] = h16(aa);                               \
            float trp = (1.f - aa * aa) * wd;                                  \
            trp += __shfl_xor(trp, 16, 64); trp += __shfl_xor(trp, 8, 64);     \
            trp += __shfl_xor(trp, 4, 64);  trp += __shfl_xor(trp, 2, 64);     \
            trp += __shfl_xor(trp, 1, 64);                                     \
            if (l == 0) wredT[par][STAGE][w] = trp;                            \
        }                                                                      \
        __syncthreads();                          /* B1: aPK + trace ready */  \
        float p0 = 0.f, p1 = 0.f, p2 = 0.f, p3 = 0.f;                          \
        G8(P4)                                                                 \
        part[q][j] = (p0 + p1) + (p2 + p3);                                    \
        __syncthreads();                          /* B2: partials ready */     \
        if (t < 128) {                                                         \
            float dx = (((part[0][t] + part[1][t]) + (part[2][t] + part[3][t]))\
                      + ((part[4][t] + part[5][t]) + (part[6][t] + part[7][t])))\
                       + b2j;                                                  \
            kx[STAGE][t] = dx;                                                 \
            float xd = xs32[t] * dx;                                           \
            RED64(xd)                                                          \
            if (l == 0) wredX[par][STAGE][w] = xd;                             \
            float xnew = (XNEW);                                               \
            xs32[t] = xnew;                                                    \
            ((unsigned short*)xsPK)[t] = h16(xnew);                            \
            EXTRA                                                              \
        }                                                                      \
        __syncthreads();                          /* B3: state advanced */     \
    }

    for (int n = 0; n < ns; ++n) {
        const float tn = (float)n;
        const int par = n & 1;

        EVAL(0, dt * tn,
             fmaf(dt, 0.2f * dx, ys[t]), ;)

        EVAL(1, dt * (tn + 0.2f),
             ys[t] + dt * (0.075f * K(0) + 0.225f * dx), ;)

        EVAL(2, dt * (tn + 0.3f),
             ys[t] + dt * ((float)(44.0/45.0)  * K(0) + (float)(-56.0/15.0) * K(1)
                         + (float)(32.0/9.0)   * dx), ;)

        EVAL(3, dt * (tn + 0.8f),
             ys[t] + dt * ((float)(19372.0/6561.0) * K(0) + (float)(-25360.0/2187.0) * K(1)
                         + (float)(64448.0/6561.0) * K(2) + (float)(-212.0/729.0)    * dx), ;)

        EVAL(4, dt * (tn + (float)(8.0/9.0)),
             ys[t] + dt * ((float)(9017.0/3168.0)  * K(0) + (float)(-355.0/33.0)     * K(1)
                         + (float)(46732.0/5247.0) * K(2) + (float)(49.0/176.0)      * K(3)
                         + (float)(-5103.0/18656.0)* dx), ;)

        EVAL(5, dt * (tn + 1.0f),
             ys[t] + dt * ((float)(35.0/384.0)     * K(0) + (float)(500.0/1113.0)   * K(2)
                         + (float)(125.0/192.0)    * K(3) + (float)(-2187.0/6784.0) * K(4)
                         + (float)(11.0/84.0)      * dx),
             ys[t] = xnew;)

        // serial tail once per STEP (thread 0), parity-double-buffered slots
        if (t == 0) {
#define TAILS(sidx, bw) { \
            float tr_ = 0.f, dv_; \
            _Pragma("unroll") \
            for (int ww = 0; ww < 16; ++ww) tr_ += wredT[par][sidx][ww]; \
            dv_ = wredX[par][sidx][0] + wredX[par][sidx][1]; \
            ld_acc += dt * (bw) * (-tr_); \
            kl_acc += dt * (bw) * (dv_ - tr_); }
            TAILS(0, (float)(35.0/384.0))
            TAILS(2, (float)(500.0/1113.0))
            TAILS(3, (float)(125.0/192.0))
            TAILS(4, (float)(-2187.0/6784.0))
            TAILS(5, (float)(11.0/84.0))
        }
    }

    // ---- outputs: z (B,D) | log_px (B) | kl (B) ----
    if (t < 128) out[s * 128 + t] = ys[t];
    if (t == 0) {
        const float LOG2PI = 1.8378770664093454f;
        float lpx0 = -0.5f * sumsq - 0.5f * 128.f * LOG2PI;
        out[nB * 128 + s]      = lpx0 + ld_acc;
        out[nB * 128 + nB + s] = kl_acc;
    }
}

extern "C" void kernel_launch(void* const* d_in, const int* in_sizes, int n_in,
                              void* d_out, int out_size, void* d_ws, size_t ws_size,
                              hipStream_t stream) {
    const float* x0 = (const float*)d_in[0];
    const float* W1 = (const float*)d_in[1];
    const float* b1 = (const float*)d_in[2];
    const float* u1 = (const float*)d_in[3];
    const float* W2 = (const float*)d_in[4];
    const float* b2 = (const float*)d_in[5];
    const int*  nsp = (const int*)d_in[6];
    float* out = (float*)d_out;
    const int nB = in_sizes[0] / 128;   // 128 samples

    hipLaunchKernelGGL(vi_node_kernel, dim3(nB), dim3(TPB), 0, stream,
                       x0, W1, b1, u1, W2, b2, nsp, out, nB);
}